// Round 19
// baseline (128.843 us; speedup 1.0000x reference)
//
#include <hip/hip_runtime.h>
#include <math.h>

#define N_POS 8192
#define FEAT 512
#define NTOT (2 * N_POS)
#define NSTEP 8    // K-steps of 64 (i8)
#define FIXS 4294967296.0   // 2^32 fixed-point scale for BCE sums

#define AS1 __attribute__((address_space(1)))
#define AS3 __attribute__((address_space(3)))

typedef __attribute__((ext_vector_type(4))) int i32x4;

__device__ inline unsigned long long packMaxI(int v, unsigned idx) {
    unsigned u = (unsigned)v ^ 0x80000000u;   // monotone int -> uint key
    return ((unsigned long long)u << 32) | (unsigned)(~idx);
}
__device__ inline unsigned unpackIdx(unsigned long long p) {
    return ~(unsigned)(p & 0xffffffffull);
}

__device__ inline int q8(float x) {
    float c = fminf(fmaxf(x * 32.0f, -127.0f), 127.0f);
    return (int)rintf(c);
}

// gather rows by idx, convert fp32 -> int8 (scale 32, RNE, clamp +-127),
// row-major [8192][512] i8; zero argmax buffers + loss accumulators
__global__ __launch_bounds__(256) void gather_convert2(
    const float* __restrict__ F0, const int* __restrict__ idx0, char* __restrict__ out0,
    const float* __restrict__ F1, const int* __restrict__ idx1, char* __restrict__ out1,
    unsigned long long* __restrict__ zbuf, unsigned long long* __restrict__ accs)
{
    if (blockIdx.x < 64) zbuf[blockIdx.x * 256 + threadIdx.x] = 0ull;
    if (blockIdx.x == 64 && threadIdx.x < 8) accs[threadIdx.x] = 0ull;
    const int per = N_POS * FEAT / 16;        // 16-B slots per matrix
    int t = blockIdx.x * 256 + threadIdx.x;
    const float* F; const int* idx; char* out;
    if (t < per) { F = F0; idx = idx0; out = out0; }
    else         { F = F1; idx = idx1; out = out1; t -= per; }
    int row = t >> 5;                          // 32 slots per row (512 i8)
    int sl  = t & 31;
    const float* src = F + (size_t)idx[row] * FEAT + sl * 16;
    i32x4 o;
    #pragma unroll
    for (int g = 0; g < 4; ++g) {
        float4 v = *(const float4*)(src + g * 4);
        int b0 = q8(v.x), b1 = q8(v.y), b2 = q8(v.z), b3 = q8(v.w);
        o[g] = (b0 & 255) | ((b1 & 255) << 8) | ((b2 & 255) << 16) | ((b3 & 255) << 24);
    }
    *(i32x4*)(out + (size_t)row * FEAT + sl * 16) = o;
}

// ---- pair-row i8 LDS layout (R12-verified, 0 conflicts), 32-line buffer ----
// Line l (128 B) holds rows {2l, 2l+1}; packed slot p = (row&1)*4 + kh,
// stored at slot s = p ^ (l&7).
__device__ inline i32x4 fragI(const char* S, int row, int kh) {
    int line = row >> 1;
    int slot = (((row & 1) << 2) | kh) ^ (line & 7);
    return *(const i32x4*)(S + line * 128 + slot * 16);
}

#define VMCNT8  asm volatile("s_waitcnt vmcnt(8)" ::: "memory")
#define VMCNT0  asm volatile("s_waitcnt vmcnt(0)" ::: "memory")

// BARRIER-FREE wave-autonomous GEMM: 1 wave/block, 64x64 tile, wave-private
// LDS double-buffers, counted vmcnt(8) (never drains mid-loop), no
// __syncthreads anywhere. Wave skew accumulates -> L2 latency de-correlates.
__global__ __launch_bounds__(64) void gemm_i8_argmax(
    const char* __restrict__ Abf, const char* __restrict__ Bbf,
    unsigned long long* __restrict__ row_best,
    unsigned long long* __restrict__ col_best)
{
    __shared__ __align__(16) char As[2][4096];   // 2 x 32 lines (64 rows x 64 k)
    __shared__ __align__(16) char Bs[2][4096];   // 16 KB total -> 10 blocks/CU

    const int lane = threadIdx.x;                // single wave
    const int l15  = lane & 15, kh = lane >> 4;

    // XCD swizzle: 16384 blocks, 128x128 tile grid; xcd slab = 16 rows x 128
    // cols, walked in col-groups of 8 (L2 set/phase: 512KB A + 256KB B)
    const int bid  = blockIdx.x;
    const int xcd  = bid & 7;
    const int loc  = bid >> 3;          // 0..2047
    const int c8   = loc & 7;
    const int r16  = (loc >> 3) & 15;
    const int cg   = loc >> 7;          // 0..15
    const int brow = (xcd * 16 + r16) * 64;
    const int bcol = (cg * 8 + c8) * 64;

    // staging decode (pair-row inverse permutation), constant per lane
    const int lineOff = lane >> 3;
    const int pp      = (lane & 7) ^ lineOff;
    const int rowOff  = lineOff * 2 + (pp >> 2);   // 0..15 within 16-row group
    const int colOff  = (pp & 3) * 16;             // i8 elements within 64-k row

    const char* Ab = Abf + (size_t)brow * FEAT;
    const char* Bb = Bbf + (size_t)bcol * FEAT;

    // one STAGE = 8 gload_lds (4 A + 4 B), each 1 KB covering 16 rows
#define STAGE(buf, t)                                                                     \
    {                                                                                     \
        _Pragma("unroll")                                                                 \
        for (int q = 0; q < 4; ++q) {                                                     \
            __builtin_amdgcn_global_load_lds(                                             \
                (const AS1 unsigned int*)(Ab +                                            \
                    (size_t)(q * 16 + rowOff) * FEAT + (t) * 64 + colOff),                \
                (AS3 unsigned int*)(&As[buf][0] + q * 1024 + lane * 16),                  \
                16, 0, 0);                                                                \
            __builtin_amdgcn_global_load_lds(                                             \
                (const AS1 unsigned int*)(Bb +                                            \
                    (size_t)(q * 16 + rowOff) * FEAT + (t) * 64 + colOff),                \
                (AS3 unsigned int*)(&Bs[buf][0] + q * 1024 + lane * 16),                  \
                16, 0, 0);                                                                \
        }                                                                                 \
    }

    i32x4 acc[4][4];
    #pragma unroll
    for (int m = 0; m < 4; ++m)
        #pragma unroll
        for (int n = 0; n < 4; ++n)
            acc[m][n] = (i32x4)0;

    STAGE(0, 0);
    STAGE(1, 1);              // 16 loads in flight

    for (int t = 0; t < NSTEP; ++t) {
        if (t < NSTEP - 1) { VMCNT8; }   // stage(t) landed; stage(t+1) flying
        else               { VMCNT0; }

        const char* Sa = &As[t & 1][0];
        const char* Sb = &Bs[t & 1][0];
        i32x4 a[4], b[4];
        #pragma unroll
        for (int i = 0; i < 4; ++i) {
            a[i] = fragI(Sa, i * 16 + l15, kh);
            b[i] = fragI(Sb, i * 16 + l15, kh);
        }
        // frags in regs before overwriting this buffer (rule #18 fence)
        asm volatile("s_waitcnt lgkmcnt(0)" ::: "memory");
        __builtin_amdgcn_sched_barrier(0);
        if (t + 2 < NSTEP) STAGE(t & 1, t + 2);   // back to 16 in flight

        #pragma unroll
        for (int m = 0; m < 4; ++m)
            #pragma unroll
            for (int n = 0; n < 4; ++n)
                acc[m][n] = __builtin_amdgcn_mfma_i32_16x16x64_i8(a[m], b[n], acc[m][n], 0, 0, 0);
    }
#undef STAGE

    // ---- fused argmax epilogue: single wave -> direct global atomics ----
    // lane holds C[row = m*16 + kh*4 + j][col = n*16 + l15] of the 64x64 tile
    #pragma unroll
    for (int m = 0; m < 4; ++m) {
        #pragma unroll
        for (int j = 0; j < 4; ++j) {
            int best = acc[m][0][j]; int bn_ = 0;
            #pragma unroll
            for (int n = 1; n < 4; ++n)
                if (acc[m][n][j] > best) { best = acc[m][n][j]; bn_ = n; }
            unsigned long long pk = packMaxI(best, (unsigned)(bcol + bn_ * 16 + l15));
            #pragma unroll
            for (int mask = 1; mask <= 8; mask <<= 1) {
                unsigned long long q = __shfl_xor(pk, mask);
                if (q > pk) pk = q;
            }
            if (l15 == 0)
                atomicMax(&row_best[brow + m * 16 + kh * 4 + j], pk);
        }
    }
    #pragma unroll
    for (int n = 0; n < 4; ++n) {
        int best = acc[0][n][0]; int bm_ = 0, bj_ = 0;
        #pragma unroll
        for (int m = 0; m < 4; ++m)
            #pragma unroll
            for (int j = 0; j < 4; ++j)
                if (acc[m][n][j] > best) { best = acc[m][n][j]; bm_ = m; bj_ = j; }
        unsigned long long pk = packMaxI(best, (unsigned)(brow + bm_ * 16 + kh * 4 + bj_));
        #pragma unroll
        for (int mask = 16; mask <= 32; mask <<= 1) {
            unsigned long long q = __shfl_xor(pk, mask);
            if (q > pk) pk = q;
        }
        if (kh == 0)
            atomicMax(&col_best[bcol + n * 16 + l15], pk);
    }
}

// 64 blocks x 256 threads, 1 item each; per-wave integer atomics (deterministic)
__global__ __launch_bounds__(256) void finalize_partial(
    const float* __restrict__ T4,
    const float* __restrict__ src_points, const float* __restrict__ tgt_points,
    const float* __restrict__ src_scores, const float* __restrict__ tgt_scores,
    const int* __restrict__ sidx, const int* __restrict__ tidx,
    const unsigned long long* __restrict__ row_best,
    const unsigned long long* __restrict__ col_best,
    unsigned long long* __restrict__ accs)
{
    const int i = blockIdx.x * 256 + threadIdx.x;
    const float R00=T4[0],R01=T4[1],R02=T4[2],t0=T4[3];
    const float R10=T4[4],R11=T4[5],R12=T4[6],t1=T4[7];
    const float R20=T4[8],R21=T4[9],R22=T4[10],t2=T4[11];

    unsigned nn = unpackIdx(i < N_POS ? row_best[i] : col_best[i - N_POS]);
    int sI, tI;
    if (i < N_POS) { sI = sidx[i];  tI = tidx[nn]; }
    else           { sI = sidx[nn]; tI = tidx[i - N_POS]; }
    float sc = (i < N_POS) ? src_scores[sI] : tgt_scores[tI];
    const float* p = src_points + (size_t)sI * 3;
    const float* q = tgt_points + (size_t)tI * 3;
    float px = R00*p[0]+R01*p[1]+R02*p[2]+t0;
    float py = R10*p[0]+R11*p[1]+R12*p[2]+t1;
    float pz = R20*p[0]+R21*p[1]+R22*p[2]+t2;
    float dx = px-q[0], dy = py-q[1], dz = pz-q[2];
    int label = (sqrtf(dx*dx+dy*dy+dz*dz) < 0.1f) ? 1 : 0;
    int res   = (sc > 0.5f) ? 1 : 0;

    double s1 = label ? (double)(-logf(sc)) : 0.0;
    double s0 = label ? 0.0 : (double)(-logf(1.0f - sc));
    int cnt = label, sr = res, co = res & label;

    #pragma unroll
    for (int off = 32; off > 0; off >>= 1) {
        s1  += __shfl_down(s1, off);
        s0  += __shfl_down(s0, off);
        cnt += __shfl_down(cnt, off);
        sr  += __shfl_down(sr, off);
        co  += __shfl_down(co, off);
    }
    if ((threadIdx.x & 63) == 0) {
        atomicAdd(&accs[0], (unsigned long long)(long long)(s1 * FIXS + 0.5));
        atomicAdd(&accs[1], (unsigned long long)(long long)(s0 * FIXS + 0.5));
        atomicAdd(&accs[2], (unsigned long long)cnt);
        atomicAdd(&accs[3], (unsigned long long)sr);
        atomicAdd(&accs[4], (unsigned long long)co);
    }
}

__global__ __launch_bounds__(64) void finalize_out(
    const unsigned long long* __restrict__ accs, float* __restrict__ out)
{
    if (threadIdx.x == 0) {
        double S1 = (double)accs[0] / FIXS;
        double S0 = (double)accs[1] / FIXS;
        float  c  = (float)accs[2];
        float  rr = (float)accs[3];
        float  co = (float)accs[4];
        float nw = c / (float)NTOT;
        out[0] = (float)((nw * S1 + (1.0 - (double)nw) * S0) / (double)NTOT);
        out[1] = co / (rr + 1e-12f);
        out[2] = co / (c + 1e-12f);
    }
}

extern "C" void kernel_launch(void* const* d_in, const int* in_sizes, int n_in,
                              void* d_out, int out_size, void* d_ws, size_t ws_size,
                              hipStream_t stream) {
    const float* T4         = (const float*)d_in[0];
    const float* src_points = (const float*)d_in[1];
    const float* tgt_points = (const float*)d_in[2];
    const float* src_scores = (const float*)d_in[3];
    const float* tgt_scores = (const float*)d_in[4];
    const float* src_feats  = (const float*)d_in[5];
    const float* tgt_feats  = (const float*)d_in[6];
    const int*   sidx       = (const int*)d_in[7];
    const int*   tidx       = (const int*)d_in[8];

    unsigned long long* row_best = (unsigned long long*)d_ws;
    unsigned long long* col_best = row_best + N_POS;
    char* Abf = (char*)d_ws + 2 * N_POS * sizeof(unsigned long long);
    char* Bbf = Abf + (size_t)N_POS * FEAT;
    unsigned long long* accs = (unsigned long long*)(Bbf + (size_t)N_POS * FEAT);
    float* out = (float*)d_out;

    hipLaunchKernelGGL(gather_convert2, dim3(2 * N_POS * FEAT / 16 / 256), dim3(256), 0, stream,
                       src_feats, sidx, Abf, tgt_feats, tidx, Bbf, row_best, accs);
    hipLaunchKernelGGL(gemm_i8_argmax, dim3(128 * 128), dim3(64), 0, stream,
                       Abf, Bbf, row_best, col_best);
    hipLaunchKernelGGL(finalize_partial, dim3(NTOT / 256), dim3(256), 0, stream,
                       T4, src_points, tgt_points, src_scores, tgt_scores,
                       sidx, tidx, row_best, col_best, accs);
    hipLaunchKernelGGL(finalize_out, dim3(1), dim3(64), 0, stream, accs, out);
}

// Round 20
// 92.517 us; speedup vs baseline: 1.3926x; 1.3926x over previous
//
#include <hip/hip_runtime.h>
#include <math.h>

#define N_POS 8192
#define FEAT 512
#define NTOT (2 * N_POS)
#define BM 128
#define BN 128
#define NSTEP 8    // K-steps of 64 (i8)
#define FIXS 4294967296.0   // 2^32 fixed-point scale for BCE sums

#define AS1 __attribute__((address_space(1)))
#define AS3 __attribute__((address_space(3)))

typedef __attribute__((ext_vector_type(4))) int i32x4;

__device__ inline unsigned long long packMaxI(int v, unsigned idx) {
    unsigned u = (unsigned)v ^ 0x80000000u;   // monotone int -> uint key
    return ((unsigned long long)u << 32) | (unsigned)(~idx);
}
__device__ inline unsigned unpackIdx(unsigned long long p) {
    return ~(unsigned)(p & 0xffffffffull);
}

__device__ inline int q8(float x) {
    float c = fminf(fmaxf(x * 32.0f, -127.0f), 127.0f);
    return (int)rintf(c);
}

// gather rows by idx, convert fp32 -> int8 (scale 32, RNE, clamp +-127),
// row-major [8192][512] i8; zero argmax buffers + loss accumulators
__global__ __launch_bounds__(256) void gather_convert2(
    const float* __restrict__ F0, const int* __restrict__ idx0, char* __restrict__ out0,
    const float* __restrict__ F1, const int* __restrict__ idx1, char* __restrict__ out1,
    unsigned long long* __restrict__ zbuf, unsigned long long* __restrict__ accs)
{
    if (blockIdx.x < 64) zbuf[blockIdx.x * 256 + threadIdx.x] = 0ull;
    if (blockIdx.x == 64 && threadIdx.x < 8) accs[threadIdx.x] = 0ull;
    const int per = N_POS * FEAT / 16;        // 16-B slots per matrix
    int t = blockIdx.x * 256 + threadIdx.x;
    const float* F; const int* idx; char* out;
    if (t < per) { F = F0; idx = idx0; out = out0; }
    else         { F = F1; idx = idx1; out = out1; t -= per; }
    int row = t >> 5;                          // 32 slots per row (512 i8)
    int sl  = t & 31;
    const float* src = F + (size_t)idx[row] * FEAT + sl * 16;
    i32x4 o;
    #pragma unroll
    for (int g = 0; g < 4; ++g) {
        float4 v = *(const float4*)(src + g * 4);
        int b0 = q8(v.x), b1 = q8(v.y), b2 = q8(v.z), b3 = q8(v.w);
        o[g] = (b0 & 255) | ((b1 & 255) << 8) | ((b2 & 255) << 16) | ((b3 & 255) << 24);
    }
    *(i32x4*)(out + (size_t)row * FEAT + sl * 16) = o;
}

// ---- pair-row i8 LDS layout, BK=64 (R12-verified, 0 conflicts) ----
// Line l (128 B) holds rows {2l, 2l+1}; packed slot p = (row&1)*4 + kh,
// stored at slot s = p ^ (l&7). Read of 16 rows x fixed kh: 2 lanes per
// 4-bank group = conflict-free (measured 0 in R12).
__device__ inline i32x4 fragI(const char* S, int row, int kh) {
    int line = row >> 1;
    int slot = (((row & 1) << 2) | kh) ^ (line & 7);
    return *(const i32x4*)(S + line * 128 + slot * 16);
}

__global__ __launch_bounds__(256, 4) void gemm_i8_argmax(
    const char* __restrict__ Abf, const char* __restrict__ Bbf,
    unsigned long long* __restrict__ row_best,
    unsigned long long* __restrict__ col_best)
{
    __shared__ __align__(16) char As[64 * 128];        // 8 KB (64 lines x 128 B)
    __shared__ __align__(16) char Bs[64 * 128];        // 8 KB
    __shared__ unsigned long long redR[BM], redC[BN];  // 2 KB -> 18 KB

    const int tid  = threadIdx.x;
    const int lane = tid & 63;
    const int w    = tid >> 6;          // 4 waves
    const int wm   = w >> 1, wn = w & 1;
    const int l15  = lane & 15, kh = lane >> 4;

    // 2-level XCD swizzle (R4-verified)
    const int bid  = blockIdx.x;
    const int xcd  = bid & 7;
    const int loc  = bid >> 3;
    const int cg   = loc >> 5;
    const int r8   = (loc & 31) >> 2;
    const int c4   = loc & 3;
    const int brow = (xcd * 8 + r8) * BM;
    const int bcol = (cg * 4 + c4) * BN;

    if (tid < BM) redR[tid] = 0ull; else redC[tid - BM] = 0ull;

    // staging decode (pair-row inverse permutation), constant per lane:
    // issue q covers lines q*8..q*8+7; lane -> lineOff = lane>>3, slotIdx = lane&7
    // content: p = slotIdx^lineOff, rowOff = lineOff*2+(p>>2), colChunk = p&3
    const int lineOff = lane >> 3;
    const int pp      = (lane & 7) ^ lineOff;
    const int rowOff  = lineOff * 2 + (pp >> 2);   // 0..15 within 16-row group
    const int colOff  = (pp & 3) * 16;             // i8 elements within 64-k row

    // wave w stages rows w*32..w*32+31 (lines w*16..+15) of A and B; 2 issues each
#define STAGE(t)                                                                          \
    {                                                                                     \
        _Pragma("unroll")                                                                 \
        for (int s = 0; s < 2; ++s) {                                                     \
            int q = w * 2 + s;                                                            \
            __builtin_amdgcn_global_load_lds(                                             \
                (const AS1 unsigned int*)(Abf +                                           \
                    (size_t)(brow + q * 16 + rowOff) * FEAT + (t) * 64 + colOff),         \
                (AS3 unsigned int*)(&As[0] + q * 1024 + lane * 16),                       \
                16, 0, 0);                                                                \
            __builtin_amdgcn_global_load_lds(                                             \
                (const AS1 unsigned int*)(Bbf +                                           \
                    (size_t)(bcol + q * 16 + rowOff) * FEAT + (t) * 64 + colOff),         \
                (AS3 unsigned int*)(&Bs[0] + q * 1024 + lane * 16),                       \
                16, 0, 0);                                                                \
        }                                                                                 \
    }

    i32x4 acc[4][4];
    #pragma unroll
    for (int m = 0; m < 4; ++m)
        #pragma unroll
        for (int n = 0; n < 4; ++n)
            acc[m][n] = (i32x4)0;

    for (int t = 0; t < NSTEP; ++t) {
        STAGE(t);
        __syncthreads();    // staged tile visible

        i32x4 a[4], b[4];
        #pragma unroll
        for (int i = 0; i < 4; ++i) {
            a[i] = fragI(&As[0], wm * 64 + i * 16 + l15, kh);
            b[i] = fragI(&Bs[0], wn * 64 + i * 16 + l15, kh);
        }
        #pragma unroll
        for (int m = 0; m < 4; ++m)
            #pragma unroll
            for (int n = 0; n < 4; ++n)
                acc[m][n] = __builtin_amdgcn_mfma_i32_16x16x64_i8(a[m], b[n], acc[m][n], 0, 0, 0);
        __syncthreads();    // all reads done before next STAGE overwrites
    }
#undef STAGE

    // ---- fused argmax epilogue ----
    // lane holds C[row = wm*64 + m*16 + kh*4 + j][col = wn*64 + n*16 + l15]
    #pragma unroll
    for (int m = 0; m < 4; ++m) {
        #pragma unroll
        for (int j = 0; j < 4; ++j) {
            int best = acc[m][0][j]; int bn_ = 0;
            #pragma unroll
            for (int n = 1; n < 4; ++n)
                if (acc[m][n][j] > best) { best = acc[m][n][j]; bn_ = n; }
            unsigned long long pk = packMaxI(best, (unsigned)(bcol + wn * 64 + bn_ * 16 + l15));
            #pragma unroll
            for (int mask = 1; mask <= 8; mask <<= 1) {
                unsigned long long q = __shfl_xor(pk, mask);
                if (q > pk) pk = q;
            }
            if (l15 == 0)
                atomicMax(&redR[wm * 64 + m * 16 + kh * 4 + j], pk);
        }
    }
    #pragma unroll
    for (int n = 0; n < 4; ++n) {
        int best = acc[0][n][0]; int bm_ = 0, bj_ = 0;
        #pragma unroll
        for (int m = 0; m < 4; ++m)
            #pragma unroll
            for (int j = 0; j < 4; ++j)
                if (acc[m][n][j] > best) { best = acc[m][n][j]; bm_ = m; bj_ = j; }
        unsigned long long pk = packMaxI(best, (unsigned)(brow + wm * 64 + bm_ * 16 + kh * 4 + bj_));
        #pragma unroll
        for (int mask = 16; mask <= 32; mask <<= 1) {
            unsigned long long q = __shfl_xor(pk, mask);
            if (q > pk) pk = q;
        }
        if (kh == 0)
            atomicMax(&redC[wn * 64 + n * 16 + l15], pk);
    }
    __syncthreads();
    if (tid < BM) atomicMax(&row_best[brow + tid], redR[tid]);
    else          atomicMax(&col_best[bcol + tid - BM], redC[tid - BM]);
}

// 64 blocks x 256 threads, 1 item each; per-wave integer atomics (deterministic)
__global__ __launch_bounds__(256) void finalize_partial(
    const float* __restrict__ T4,
    const float* __restrict__ src_points, const float* __restrict__ tgt_points,
    const float* __restrict__ src_scores, const float* __restrict__ tgt_scores,
    const int* __restrict__ sidx, const int* __restrict__ tidx,
    const unsigned long long* __restrict__ row_best,
    const unsigned long long* __restrict__ col_best,
    unsigned long long* __restrict__ accs)
{
    const int i = blockIdx.x * 256 + threadIdx.x;
    const float R00=T4[0],R01=T4[1],R02=T4[2],t0=T4[3];
    const float R10=T4[4],R11=T4[5],R12=T4[6],t1=T4[7];
    const float R20=T4[8],R21=T4[9],R22=T4[10],t2=T4[11];

    unsigned nn = unpackIdx(i < N_POS ? row_best[i] : col_best[i - N_POS]);
    int sI, tI;
    if (i < N_POS) { sI = sidx[i];  tI = tidx[nn]; }
    else           { sI = sidx[nn]; tI = tidx[i - N_POS]; }
    float sc = (i < N_POS) ? src_scores[sI] : tgt_scores[tI];
    const float* p = src_points + (size_t)sI * 3;
    const float* q = tgt_points + (size_t)tI * 3;
    float px = R00*p[0]+R01*p[1]+R02*p[2]+t0;
    float py = R10*p[0]+R11*p[1]+R12*p[2]+t1;
    float pz = R20*p[0]+R21*p[1]+R22*p[2]+t2;
    float dx = px-q[0], dy = py-q[1], dz = pz-q[2];
    int label = (sqrtf(dx*dx+dy*dy+dz*dz) < 0.1f) ? 1 : 0;
    int res   = (sc > 0.5f) ? 1 : 0;

    double s1 = label ? (double)(-logf(sc)) : 0.0;
    double s0 = label ? 0.0 : (double)(-logf(1.0f - sc));
    int cnt = label, sr = res, co = res & label;

    #pragma unroll
    for (int off = 32; off > 0; off >>= 1) {
        s1  += __shfl_down(s1, off);
        s0  += __shfl_down(s0, off);
        cnt += __shfl_down(cnt, off);
        sr  += __shfl_down(sr, off);
        co  += __shfl_down(co, off);
    }
    if ((threadIdx.x & 63) == 0) {
        atomicAdd(&accs[0], (unsigned long long)(long long)(s1 * FIXS + 0.5));
        atomicAdd(&accs[1], (unsigned long long)(long long)(s0 * FIXS + 0.5));
        atomicAdd(&accs[2], (unsigned long long)cnt);
        atomicAdd(&accs[3], (unsigned long long)sr);
        atomicAdd(&accs[4], (unsigned long long)co);
    }
}

__global__ __launch_bounds__(64) void finalize_out(
    const unsigned long long* __restrict__ accs, float* __restrict__ out)
{
    if (threadIdx.x == 0) {
        double S1 = (double)accs[0] / FIXS;
        double S0 = (double)accs[1] / FIXS;
        float  c  = (float)accs[2];
        float  rr = (float)accs[3];
        float  co = (float)accs[4];
        float nw = c / (float)NTOT;
        out[0] = (float)((nw * S1 + (1.0 - (double)nw) * S0) / (double)NTOT);
        out[1] = co / (rr + 1e-12f);
        out[2] = co / (c + 1e-12f);
    }
}

extern "C" void kernel_launch(void* const* d_in, const int* in_sizes, int n_in,
                              void* d_out, int out_size, void* d_ws, size_t ws_size,
                              hipStream_t stream) {
    const float* T4         = (const float*)d_in[0];
    const float* src_points = (const float*)d_in[1];
    const float* tgt_points = (const float*)d_in[2];
    const float* src_scores = (const float*)d_in[3];
    const float* tgt_scores = (const float*)d_in[4];
    const float* src_feats  = (const float*)d_in[5];
    const float* tgt_feats  = (const float*)d_in[6];
    const int*   sidx       = (const int*)d_in[7];
    const int*   tidx       = (const int*)d_in[8];

    unsigned long long* row_best = (unsigned long long*)d_ws;
    unsigned long long* col_best = row_best + N_POS;
    char* Abf = (char*)d_ws + 2 * N_POS * sizeof(unsigned long long);
    char* Bbf = Abf + (size_t)N_POS * FEAT;
    unsigned long long* accs = (unsigned long long*)(Bbf + (size_t)N_POS * FEAT);
    float* out = (float*)d_out;

    hipLaunchKernelGGL(gather_convert2, dim3(2 * N_POS * FEAT / 16 / 256), dim3(256), 0, stream,
                       src_feats, sidx, Abf, tgt_feats, tidx, Bbf, row_best, accs);
    hipLaunchKernelGGL(gemm_i8_argmax, dim3((N_POS / BM) * (N_POS / BN)), dim3(256), 0, stream,
                       Abf, Bbf, row_best, col_best);
    hipLaunchKernelGGL(finalize_partial, dim3(NTOT / 256), dim3(256), 0, stream,
                       T4, src_points, tgt_points, src_scores, tgt_scores,
                       sidx, tidx, row_best, col_best, accs);
    hipLaunchKernelGGL(finalize_out, dim3(1), dim3(64), 0, stream, accs, out);
}